// Round 3
// baseline (387.672 us; speedup 1.0000x reference)
//
#include <hip/hip_runtime.h>
#include <math.h>

#define BB 16
#define TT 24
#define NN 2048
#define FF 64
#define BT (BB*TT)        // 384
#define T2 (TT*TT)        // 576
#define NF4 (NN*FF/4)     // 32768 float4 per (b,t) slab

// workspace layout (floats)
// t1 partials:  [4 chunks][BT][FF]
// rhs2 partials:[4 chunks][BT][FF]
#define WS_T1P  0
#define WS_R2P  (WS_T1P + 4*BT*FF)     // 98304

typedef float vfloat4 __attribute__((ext_vector_type(4)));

__device__ __forceinline__ float4 f4zero() { return make_float4(0.f,0.f,0.f,0.f); }

__device__ __forceinline__ void nt_store_f4(float4 v, float4* p) {
    vfloat4 nv;
    nv.x = v.x; nv.y = v.y; nv.z = v.z; nv.w = v.w;
    __builtin_nontemporal_store(nv, (vfloat4*)p);
}

// ---------------------------------------------------------------------------
// Kernel 1: read x once; produce per-chunk partials
//   t1p[c][bt][f]   = sum_{n in chunk c} x[bt][n][f] * U1[n]
//   r2p[c][bt][f]   = sum_{n in chunk c} rhs[bt][n] * U2[n][f]
//                     where rhs[bt][n] = sum_f x[bt][n][f]*U3[f]
// The butterfly reduce of rhs leaves the row-dot in ALL 16 lanes of the
// row-group, so the rhs2 contraction costs one extra U2 float4 load (L2-hot)
// + 4 FMAs per iteration. rhs never touches global memory.
// grid (BT, 4), block 256.  lane = rowg*16 + fq; 4 rows/wave; fq = f-quad.
// ---------------------------------------------------------------------------
__global__ __launch_bounds__(256) void k_stage1(
    const float4* __restrict__ x4, const float* __restrict__ U1,
    const float4* __restrict__ U3_4, const float4* __restrict__ U2_4,
    float4* __restrict__ t1p, float4* __restrict__ r2p)
{
    const int bt    = blockIdx.x;
    const int chunk = blockIdx.y;
    const int nbase = chunk * 512;
    const int tid   = threadIdx.x;
    const int wave  = tid >> 6;
    const int lane  = tid & 63;
    const int rowg  = lane >> 4;
    const int fq    = lane & 15;

    const float4 u3 = U3_4[fq];
    float4 t1a = f4zero();
    float4 r2a = f4zero();
    const float4* xb = x4 + (size_t)bt * NF4;

    for (int i = 0; i < 32; ++i) {
        const int n = nbase + i*16 + wave*4 + rowg;
        const float4 xv = xb[(size_t)n*16 + fq];
        const float u1n = U1[n];
        t1a.x += xv.x*u1n; t1a.y += xv.y*u1n; t1a.z += xv.z*u1n; t1a.w += xv.w*u1n;
        float r = xv.x*u3.x + xv.y*u3.y + xv.z*u3.z + xv.w*u3.w;
        r += __shfl_xor(r, 8);
        r += __shfl_xor(r, 4);
        r += __shfl_xor(r, 2);
        r += __shfl_xor(r, 1);          // full row-dot now in all 16 lanes
        const float4 u2 = U2_4[(size_t)n*16 + fq];
        r2a.x += r*u2.x; r2a.y += r*u2.y; r2a.z += r*u2.z; r2a.w += r*u2.w;
    }
    // combine the 4 row-groups within the wave (lane bits 4,5)
    t1a.x += __shfl_xor(t1a.x, 16); t1a.y += __shfl_xor(t1a.y, 16);
    t1a.z += __shfl_xor(t1a.z, 16); t1a.w += __shfl_xor(t1a.w, 16);
    t1a.x += __shfl_xor(t1a.x, 32); t1a.y += __shfl_xor(t1a.y, 32);
    t1a.z += __shfl_xor(t1a.z, 32); t1a.w += __shfl_xor(t1a.w, 32);
    r2a.x += __shfl_xor(r2a.x, 16); r2a.y += __shfl_xor(r2a.y, 16);
    r2a.z += __shfl_xor(r2a.z, 16); r2a.w += __shfl_xor(r2a.w, 16);
    r2a.x += __shfl_xor(r2a.x, 32); r2a.y += __shfl_xor(r2a.y, 32);
    r2a.z += __shfl_xor(r2a.z, 32); r2a.w += __shfl_xor(r2a.w, 32);

    __shared__ float4 redT[4][16];
    __shared__ float4 redR[4][16];
    if (lane < 16) { redT[wave][lane] = t1a; redR[wave][lane] = r2a; }
    __syncthreads();
    if (tid < 16) {
        const float4 s0 = redT[0][tid], s1 = redT[1][tid], s2 = redT[2][tid], s3 = redT[3][tid];
        float4 tot;
        tot.x = s0.x+s1.x+s2.x+s3.x; tot.y = s0.y+s1.y+s2.y+s3.y;
        tot.z = s0.z+s1.z+s2.z+s3.z; tot.w = s0.w+s1.w+s2.w+s3.w;
        t1p[((size_t)chunk*BT + bt)*16 + tid] = tot;      // partial: no atomics, no memset
    } else if (tid < 32) {
        const int q = tid - 16;
        const float4 s0 = redR[0][q], s1 = redR[1][q], s2 = redR[2][q], s3 = redR[3][q];
        float4 tot;
        tot.x = s0.x+s1.x+s2.x+s3.x; tot.y = s0.y+s1.y+s2.y+s3.y;
        tot.z = s0.z+s1.z+s2.z+s3.z; tot.w = s0.w+s1.w+s2.w+s3.w;
        r2p[((size_t)chunk*BT + bt)*16 + q] = tot;
    }
}

// ---------------------------------------------------------------------------
// Kernel 2 (fused attn + out): per block, recompute A(b) from the tiny
// t1p/r2p partials (786 KB working set, L2/L3-hot -> ~2-3 us concurrent
// prologue across all blocks), then stream x and produce out.
//   t1[i][f]   = sum_c t1p[c][b*24+i][f]
//   rhs2[j][f] = sum_c r2p[c][b*24+j][f]
//   sig[i][j]  = sigmoid( sum_f t1[i][f]*rhs2[j][f] + be[i][j] )
//   E[t][r]    = sum_s Ve[t][s]*sig[s][r];  A = softmax over t
//   out[b][s][n][f] = sum_t x[b][t][n][f] * A[t][s]
// grid (128, B), block 256; one float4 of (n,f) per thread, 24 accumulators.
// A never touches global memory.
// ---------------------------------------------------------------------------
__global__ __launch_bounds__(256) void k_out(
    const float4* __restrict__ x4,
    const float* __restrict__ t1p, const float* __restrict__ r2p,
    const float* __restrict__ be, const float* __restrict__ Ve,
    float4* __restrict__ out4)
{
    const int b   = blockIdx.y;
    const int tid = threadIdx.x;
    const int idx = blockIdx.x*256 + tid;            // 0 .. NF4-1

    __shared__ float t1s[TT*FF];      // broadcast reads -> no pad needed
    __shared__ float r2s[TT*65];      // padded: column reads across j
    __shared__ float VeL[T2];
    __shared__ float sigL[TT*25];
    __shared__ float EL[TT*25];
    __shared__ float Af[TT*TT];       // A[t][s], rows 96 B -> 16B-aligned

    // --- phase 1: reduce partials into LDS ---
    for (int q = tid; q < TT*FF; q += 256) {
        const size_t base = (size_t)b*TT*FF + q;
        t1s[q] = t1p[base] + t1p[base + BT*FF] + t1p[base + 2*BT*FF] + t1p[base + 3*BT*FF];
        const float s2 = r2p[base] + r2p[base + BT*FF] + r2p[base + 2*BT*FF] + r2p[base + 3*BT*FF];
        r2s[(q >> 6)*65 + (q & 63)] = s2;
    }
    for (int q = tid; q < T2; q += 256) VeL[q] = Ve[q];
    __syncthreads();

    // --- phase 2: sig[i][j] ---
    for (int q = tid; q < T2; q += 256) {
        const int i = q / TT, j = q % TT;
        float p = 0.f;
        #pragma unroll
        for (int f = 0; f < FF; ++f) p += t1s[i*FF + f] * r2s[j*65 + f];
        sigL[i*25 + j] = 1.0f / (1.0f + expf(-(p + be[q])));
    }
    __syncthreads();

    // --- phase 3: E[i][j] ---
    for (int q = tid; q < T2; q += 256) {
        const int i = q / TT, j = q % TT;
        float E = 0.f;
        #pragma unroll
        for (int s = 0; s < TT; ++s) E += VeL[i*TT + s] * sigL[s*25 + j];
        EL[i*25 + j] = E;
    }
    __syncthreads();

    // --- phase 4: softmax over t (column j), write A[t][s] ---
    for (int q = tid; q < T2; q += 256) {
        const int i = q / TT, j = q % TT;
        float m = -1e30f;
        #pragma unroll
        for (int t = 0; t < TT; ++t) m = fmaxf(m, EL[t*25 + j]);
        float ssum = 0.f;
        #pragma unroll
        for (int t = 0; t < TT; ++t) ssum += expf(EL[t*25 + j] - m);
        Af[q] = expf(EL[i*25 + j] - m) / ssum;   // A[t=i][s=j]
    }
    __syncthreads();

    // --- phase 5: stream x, accumulate out ---
    const float4* xb = x4 + (size_t)b*TT*NF4;
    const float4* A4 = (const float4*)Af;            // [t][6] float4
    float4 acc[TT];
    #pragma unroll
    for (int s = 0; s < TT; ++s) acc[s] = f4zero();

    for (int t = 0; t < TT; ++t) {
        const float4 xv = xb[(size_t)t*NF4 + idx];
        #pragma unroll
        for (int sq = 0; sq < 6; ++sq) {
            const float4 a = A4[t*6 + sq];           // A[t][4sq..4sq+3]
            acc[4*sq+0].x += xv.x*a.x; acc[4*sq+0].y += xv.y*a.x;
            acc[4*sq+0].z += xv.z*a.x; acc[4*sq+0].w += xv.w*a.x;
            acc[4*sq+1].x += xv.x*a.y; acc[4*sq+1].y += xv.y*a.y;
            acc[4*sq+1].z += xv.z*a.y; acc[4*sq+1].w += xv.w*a.y;
            acc[4*sq+2].x += xv.x*a.z; acc[4*sq+2].y += xv.y*a.z;
            acc[4*sq+2].z += xv.z*a.z; acc[4*sq+2].w += xv.w*a.z;
            acc[4*sq+3].x += xv.x*a.w; acc[4*sq+3].y += xv.y*a.w;
            acc[4*sq+3].z += xv.z*a.w; acc[4*sq+3].w += xv.w*a.w;
        }
    }
    float4* ob = out4 + (size_t)b*TT*NF4;
    #pragma unroll
    for (int s = 0; s < TT; ++s)
        nt_store_f4(acc[s], &ob[(size_t)s*NF4 + idx]);
}

// ---------------------------------------------------------------------------
extern "C" void kernel_launch(void* const* d_in, const int* in_sizes, int n_in,
                              void* d_out, int out_size, void* d_ws, size_t ws_size,
                              hipStream_t stream)
{
    const float* x  = (const float*)d_in[0];
    const float* U1 = (const float*)d_in[1];
    const float* U2 = (const float*)d_in[2];
    const float* U3 = (const float*)d_in[3];
    const float* be = (const float*)d_in[4];
    const float* Ve = (const float*)d_in[5];

    float* ws   = (float*)d_ws;
    float* t1p  = ws + WS_T1P;
    float* r2p  = ws + WS_R2P;

    // 2 dispatches total.
    k_stage1<<<dim3(BT, 4), 256, 0, stream>>>(
        (const float4*)x, U1, (const float4*)U3, (const float4*)U2,
        (float4*)t1p, (float4*)r2p);
    k_out<<<dim3(NF4/256, BB), 256, 0, stream>>>(
        (const float4*)x, t1p, r2p, be, Ve, (float4*)d_out);
}

// Round 4
// 378.625 us; speedup vs baseline: 1.0239x; 1.0239x over previous
//
#include <hip/hip_runtime.h>
#include <math.h>

#define BB 16
#define TT 24
#define NN 2048
#define FF 64
#define BT (BB*TT)        // 384
#define T2 (TT*TT)        // 576
#define NF4 (NN*FF/4)     // 32768 float4 per (b,t) slab

// workspace layout (floats)
// t1 partials:  [4 chunks][BT][FF]
// rhs2 partials:[4 chunks][BT][FF]
// A matrix:     [BB][T2]
#define WS_T1P  0
#define WS_R2P  (WS_T1P + 4*BT*FF)     // 98304
#define WS_AMAT (WS_R2P + 4*BT*FF)     // 196608

typedef float vfloat4 __attribute__((ext_vector_type(4)));
typedef float vfloat2 __attribute__((ext_vector_type(2)));

__device__ __forceinline__ float4 f4zero() { return make_float4(0.f,0.f,0.f,0.f); }

// ---------------------------------------------------------------------------
// Kernel 1: read x once; produce per-chunk partials
//   t1p[c][bt][f]   = sum_{n in chunk c} x[bt][n][f] * U1[n]
//   r2p[c][bt][f]   = sum_{n in chunk c} rhs[bt][n] * U2[n][f]
//                     where rhs[bt][n] = sum_f x[bt][n][f]*U3[f]
// grid (BT, 4), block 256.  lane = rowg*16 + fq; 4 rows/wave; fq = f-quad.
// ---------------------------------------------------------------------------
__global__ __launch_bounds__(256) void k_stage1(
    const float4* __restrict__ x4, const float* __restrict__ U1,
    const float4* __restrict__ U3_4, const float4* __restrict__ U2_4,
    float4* __restrict__ t1p, float4* __restrict__ r2p)
{
    const int bt    = blockIdx.x;
    const int chunk = blockIdx.y;
    const int nbase = chunk * 512;
    const int tid   = threadIdx.x;
    const int wave  = tid >> 6;
    const int lane  = tid & 63;
    const int rowg  = lane >> 4;
    const int fq    = lane & 15;

    const float4 u3 = U3_4[fq];
    float4 t1a = f4zero();
    float4 r2a = f4zero();
    const float4* xb = x4 + (size_t)bt * NF4;

    for (int i = 0; i < 32; ++i) {
        const int n = nbase + i*16 + wave*4 + rowg;
        const float4 xv = xb[(size_t)n*16 + fq];
        const float u1n = U1[n];
        t1a.x += xv.x*u1n; t1a.y += xv.y*u1n; t1a.z += xv.z*u1n; t1a.w += xv.w*u1n;
        float r = xv.x*u3.x + xv.y*u3.y + xv.z*u3.z + xv.w*u3.w;
        r += __shfl_xor(r, 8);
        r += __shfl_xor(r, 4);
        r += __shfl_xor(r, 2);
        r += __shfl_xor(r, 1);          // full row-dot now in all 16 lanes
        const float4 u2 = U2_4[(size_t)n*16 + fq];
        r2a.x += r*u2.x; r2a.y += r*u2.y; r2a.z += r*u2.z; r2a.w += r*u2.w;
    }
    // combine the 4 row-groups within the wave (lane bits 4,5)
    t1a.x += __shfl_xor(t1a.x, 16); t1a.y += __shfl_xor(t1a.y, 16);
    t1a.z += __shfl_xor(t1a.z, 16); t1a.w += __shfl_xor(t1a.w, 16);
    t1a.x += __shfl_xor(t1a.x, 32); t1a.y += __shfl_xor(t1a.y, 32);
    t1a.z += __shfl_xor(t1a.z, 32); t1a.w += __shfl_xor(t1a.w, 32);
    r2a.x += __shfl_xor(r2a.x, 16); r2a.y += __shfl_xor(r2a.y, 16);
    r2a.z += __shfl_xor(r2a.z, 16); r2a.w += __shfl_xor(r2a.w, 16);
    r2a.x += __shfl_xor(r2a.x, 32); r2a.y += __shfl_xor(r2a.y, 32);
    r2a.z += __shfl_xor(r2a.z, 32); r2a.w += __shfl_xor(r2a.w, 32);

    __shared__ float4 redT[4][16];
    __shared__ float4 redR[4][16];
    if (lane < 16) { redT[wave][lane] = t1a; redR[wave][lane] = r2a; }
    __syncthreads();
    if (tid < 16) {
        const float4 s0 = redT[0][tid], s1 = redT[1][tid], s2 = redT[2][tid], s3 = redT[3][tid];
        float4 tot;
        tot.x = s0.x+s1.x+s2.x+s3.x; tot.y = s0.y+s1.y+s2.y+s3.y;
        tot.z = s0.z+s1.z+s2.z+s3.z; tot.w = s0.w+s1.w+s2.w+s3.w;
        t1p[((size_t)chunk*BT + bt)*16 + tid] = tot;      // partial: no atomics, no memset
    } else if (tid < 32) {
        const int q = tid - 16;
        const float4 s0 = redR[0][q], s1 = redR[1][q], s2 = redR[2][q], s3 = redR[3][q];
        float4 tot;
        tot.x = s0.x+s1.x+s2.x+s3.x; tot.y = s0.y+s1.y+s2.y+s3.y;
        tot.z = s0.z+s1.z+s2.z+s3.z; tot.w = s0.w+s1.w+s2.w+s3.w;
        r2p[((size_t)chunk*BT + bt)*16 + q] = tot;
    }
}

// ---------------------------------------------------------------------------
// Kernel 2 (fused lhs/prod/softmax): per batch b
//   t1[i][f]   = sum_c t1p[c][b*24+i][f]
//   rhs2[j][f] = sum_c r2p[c][b*24+j][f]
//   sig[i][j]  = sigmoid( sum_f t1[i][f]*rhs2[j][f] + be[i][j] )
//   E[t][r]    = sum_s Ve[t][s]*sig[s][r];  A = softmax over t
// one block per b, 576 threads (i = tid/24, j = tid%24).
// ---------------------------------------------------------------------------
__global__ __launch_bounds__(576) void k_attn(
    const float* __restrict__ t1p, const float* __restrict__ r2p,
    const float* __restrict__ be, const float* __restrict__ Ve,
    float* __restrict__ Amat)
{
    const int b = blockIdx.x, tid = threadIdx.x;
    __shared__ float t1s[TT*FF];      // broadcast reads -> no pad needed
    __shared__ float r2s[TT*65];      // padded: column reads across j
    __shared__ float VeL[T2];
    __shared__ float sigL[TT*25];
    __shared__ float EL[TT*25];
    __shared__ float eL[TT*25];

    for (int idx = tid; idx < TT*FF; idx += 576) {
        const size_t base = (size_t)b*TT*FF + idx;
        t1s[idx] = t1p[base] + t1p[base + BT*FF] + t1p[base + 2*BT*FF] + t1p[base + 3*BT*FF];
        const float s2 = r2p[base] + r2p[base + BT*FF] + r2p[base + 2*BT*FF] + r2p[base + 3*BT*FF];
        r2s[(idx >> 6)*65 + (idx & 63)] = s2;
    }
    VeL[tid] = Ve[tid];
    __syncthreads();

    const int i = tid / TT, j = tid % TT;
    float p = 0.f;
    #pragma unroll
    for (int f = 0; f < FF; ++f) p += t1s[i*FF + f] * r2s[j*65 + f];
    const float sg = 1.0f / (1.0f + expf(-(p + be[tid])));
    sigL[i*25 + j] = sg;
    __syncthreads();

    float E = 0.f;
    #pragma unroll
    for (int s = 0; s < TT; ++s) E += VeL[i*TT + s] * sigL[s*25 + j];
    EL[i*25 + j] = E;
    __syncthreads();

    float m = -1e30f;
    #pragma unroll
    for (int tt = 0; tt < TT; ++tt) m = fmaxf(m, EL[tt*25 + j]);
    const float e = expf(E - m);
    eL[i*25 + j] = e;
    __syncthreads();

    float ssum = 0.f;
    #pragma unroll
    for (int tt = 0; tt < TT; ++tt) ssum += eL[tt*25 + j];
    Amat[(size_t)b*T2 + tid] = e / ssum;
}

// ---------------------------------------------------------------------------
// Kernel 3: out[b][s][n][f] = sum_t x[b][t][n][f] * A[b][t][s]
// grid (128, B), block 256; one float4 of (n,f) per thread, 24 accumulators.
// Accumulation written as <2 x float> vector ops so the backend can emit
// v_pk_fma_f32 (2 FMAs/inst) with the A-splat folded into op_sel —
// halves k_out's VALU instruction count (96 -> 48 per t-iter).
// Nontemporal stores keep x L3-resident (read again here after k_stage1).
// ---------------------------------------------------------------------------
__global__ __launch_bounds__(256) void k_out(
    const float4* __restrict__ x4, const float4* __restrict__ Amat4,
    float4* __restrict__ out4)
{
    const int b   = blockIdx.y;
    const int idx = blockIdx.x*256 + threadIdx.x;    // 0 .. NF4-1

    __shared__ float4 A4[TT*6];                      // 24 rows x 6 float4
    if (threadIdx.x < TT*6) A4[threadIdx.x] = Amat4[(size_t)b*TT*6 + threadIdx.x];
    __syncthreads();

    const float4* xb = x4 + (size_t)b*TT*NF4;
    vfloat2 acc[TT*2];                               // [s][half], unrolled idx only
    #pragma unroll
    for (int s = 0; s < TT*2; ++s) acc[s] = (vfloat2){0.f, 0.f};

    for (int t = 0; t < TT; ++t) {
        const float4 xv = xb[(size_t)t*NF4 + idx];
        const vfloat2 x01 = {xv.x, xv.y};
        const vfloat2 x23 = {xv.z, xv.w};
        #pragma unroll
        for (int sq = 0; sq < 6; ++sq) {
            const float4 a = A4[t*6 + sq];           // A[t][4sq..4sq+3]
            const vfloat2 ax = {a.x, a.x};
            const vfloat2 ay = {a.y, a.y};
            const vfloat2 az = {a.z, a.z};
            const vfloat2 aw = {a.w, a.w};
            acc[(4*sq+0)*2+0] += x01*ax;  acc[(4*sq+0)*2+1] += x23*ax;
            acc[(4*sq+1)*2+0] += x01*ay;  acc[(4*sq+1)*2+1] += x23*ay;
            acc[(4*sq+2)*2+0] += x01*az;  acc[(4*sq+2)*2+1] += x23*az;
            acc[(4*sq+3)*2+0] += x01*aw;  acc[(4*sq+3)*2+1] += x23*aw;
        }
    }
    float4* ob = out4 + (size_t)b*TT*NF4;
    #pragma unroll
    for (int s = 0; s < TT; ++s) {
        vfloat4 nv;
        nv.x = acc[s*2+0].x; nv.y = acc[s*2+0].y;
        nv.z = acc[s*2+1].x; nv.w = acc[s*2+1].y;
        __builtin_nontemporal_store(nv, (vfloat4*)&ob[(size_t)s*NF4 + idx]);
    }
}

// ---------------------------------------------------------------------------
extern "C" void kernel_launch(void* const* d_in, const int* in_sizes, int n_in,
                              void* d_out, int out_size, void* d_ws, size_t ws_size,
                              hipStream_t stream)
{
    const float* x  = (const float*)d_in[0];
    const float* U1 = (const float*)d_in[1];
    const float* U2 = (const float*)d_in[2];
    const float* U3 = (const float*)d_in[3];
    const float* be = (const float*)d_in[4];
    const float* Ve = (const float*)d_in[5];

    float* ws   = (float*)d_ws;
    float* t1p  = ws + WS_T1P;
    float* r2p  = ws + WS_R2P;
    float* Am   = ws + WS_AMAT;

    // 3 dispatches total.
    k_stage1<<<dim3(BT, 4), 256, 0, stream>>>(
        (const float4*)x, U1, (const float4*)U3, (const float4*)U2,
        (float4*)t1p, (float4*)r2p);
    k_attn<<<dim3(BB), 576, 0, stream>>>(t1p, r2p, be, Ve, Am);
    k_out<<<dim3(NF4/256, BB), 256, 0, stream>>>(
        (const float4*)x, (const float4*)Am, (float4*)d_out);
}